// Round 11
// baseline (240.288 us; speedup 1.0000x reference)
//
#include <hip/hip_runtime.h>
#include <hip/hip_bf16.h>

typedef unsigned int u32;
typedef unsigned short u16;
typedef __bf16 bf16x8 __attribute__((ext_vector_type(8)));
typedef float f32x4 __attribute__((ext_vector_type(4)));
typedef _Float16 f16;
typedef _Float16 f16x2 __attribute__((ext_vector_type(2)));
typedef _Float16 f16x4 __attribute__((ext_vector_type(4)));

#define B_ 4
#define T_ 2048
#define C_ 1024
#define H_ 16
#define HD_ 64
#define M_ (B_*T_)
#define N3C (3*C_)
#define N2C (2*C_)

__device__ __forceinline__ u16 f2bf(float f) {
  u32 u = __builtin_bit_cast(u32, f);
  u = (u + 0x7fffu + ((u >> 16) & 1u)) >> 16;
  return (u16)u;
}

#define GLD16(gp, lp) __builtin_amdgcn_global_load_lds( \
    (const __attribute__((address_space(1))) u32*)(gp), \
    (__attribute__((address_space(3))) u32*)(lp), 16, 0, 0)

#if __has_builtin(__builtin_amdgcn_exp2f)
#define EXP2F(x) __builtin_amdgcn_exp2f(x)
#else
#define EXP2F(x) exp2f(x)
#endif

// ------- fused prep: x->bf16 cvt + W_attn^T + W_proj^T (one launch) -------
__global__ __launch_bounds__(256) void prep(
    const float* __restrict__ x, const float* __restrict__ Wa,
    const float* __restrict__ Wp,
    u16* __restrict__ xb, u16* __restrict__ W1t, u16* __restrict__ W2t) {
  __shared__ float t[32][33];
  const int blk = blockIdx.x, tid = threadIdx.x;
  if (blk < 8192) {
    int i = blk * 256 + tid;
    float4 v = ((const float4*)x)[i];
    ushort4 o;
    o.x = f2bf(v.x); o.y = f2bf(v.y); o.z = f2bf(v.z); o.w = f2bf(v.w);
    ((ushort4*)xb)[i] = o;
    return;
  }
  const float* W; u16* Wt; int Ndim, id;
  if (blk < 8192 + 3072) { W = Wa; Wt = W1t; Ndim = N3C; id = blk - 8192; }
  else                   { W = Wp; Wt = W2t; Ndim = C_;  id = blk - 11264; }
  const int nt = Ndim / 32;
  const int n0 = (id % nt) * 32, k0 = (id / nt) * 32;
  const int tx = tid & 31, ty = tid >> 5;
  #pragma unroll
  for (int i = ty; i < 32; i += 8)
    t[i][tx] = W[(long)(k0 + i) * Ndim + n0 + tx];
  __syncthreads();
  #pragma unroll
  for (int i = ty; i < 32; i += 8)
    Wt[(long)(n0 + i) * C_ + k0 + tx] = f2bf(t[tx][i]);
}

// -------- qkv GEMM: 128x128 tile; q/k cols -> bf16 qk[M][2C], v -> f16 vt ----
__global__ __launch_bounds__(256) void gemm_qkv(
    const u16* __restrict__ A, const u16* __restrict__ Bt,
    const float* __restrict__ bias, u16* __restrict__ qkout,
    f16* __restrict__ vt) {
  __shared__ u16 As[128 * 64];
  __shared__ u16 Bs[128 * 64];
  const int tid = threadIdx.x;
  const int wave = tid >> 6, lane = tid & 63;
  const int wm = wave >> 1, wn = wave & 1;
  const int l15 = lane & 15, quad = lane >> 4;
  const int rA = lane >> 3, cxor = (lane & 7) ^ rA;
  const long rowA0 = (long)blockIdx.x * 128;
  const long colB0 = (long)blockIdx.y * 128;
  const int K = C_;

  f32x4 acc[4][4] = {};

  const u16* Ag = A + (rowA0 + wave * 32 + rA) * K + cxor * 8;
  const u16* Bg = Bt + (colB0 + wave * 32 + rA) * K + cxor * 8;
  u16* Asw = &As[(wave * 32) * 64];
  u16* Bsw = &Bs[(wave * 32) * 64];

  const int fbase = l15 * 64 + ((quad ^ (l15 & 3)) << 3) + (((l15 >> 2) & 1) << 5);
  const int aA0 = wm * 4096 + fbase, aA1 = aA0 ^ 32;
  const int bA0 = wn * 4096 + fbase, bA1 = bA0 ^ 32;

  for (int k0 = 0; k0 < K; k0 += 64) {
    #pragma unroll
    for (int j = 0; j < 4; ++j) {
      GLD16(Ag + (long)j * 8 * K + k0, Asw + j * 8 * 64);
      GLD16(Bg + (long)j * 8 * K + k0, Bsw + j * 8 * 64);
    }
    __syncthreads();
    #pragma unroll
    for (int kk = 0; kk < 2; ++kk) {
      const int ai = kk ? aA1 : aA0;
      const int bi = kk ? bA1 : bA0;
      bf16x8 af[4], bfr[4];
      #pragma unroll
      for (int mt = 0; mt < 4; ++mt)
        af[mt] = *(const bf16x8*)&As[ai + mt * 1024];
      #pragma unroll
      for (int nt = 0; nt < 4; ++nt)
        bfr[nt] = *(const bf16x8*)&Bs[bi + nt * 1024];
      #pragma unroll
      for (int mt = 0; mt < 4; ++mt)
        #pragma unroll
        for (int nt = 0; nt < 4; ++nt)
          acc[mt][nt] = __builtin_amdgcn_mfma_f32_16x16x32_bf16(
              af[mt], bfr[nt], acc[mt][nt], 0, 0, 0);
    }
    __syncthreads();
  }

  float bl[4];
  #pragma unroll
  for (int nt = 0; nt < 4; ++nt)
    bl[nt] = bias[colB0 + wn * 64 + nt * 16 + l15];

  const bool vmode = (colB0 >= N2C);  // block-uniform
  #pragma unroll
  for (int mt = 0; mt < 4; ++mt) {
    long row = rowA0 + wm * 64 + mt * 16 + quad * 4;
    #pragma unroll
    for (int nt = 0; nt < 4; ++nt) {
      long col = colB0 + wn * 64 + nt * 16 + l15;
      float v0 = acc[mt][nt][0] + bl[nt];
      float v1 = acc[mt][nt][1] + bl[nt];
      float v2 = acc[mt][nt][2] + bl[nt];
      float v3 = acc[mt][nt][3] + bl[nt];
      if (!vmode) {
        qkout[(row + 0) * N2C + col] = f2bf(v0);
        qkout[(row + 1) * N2C + col] = f2bf(v1);
        qkout[(row + 2) * N2C + col] = f2bf(v2);
        qkout[(row + 3) * N2C + col] = f2bf(v3);
      } else {
        int cv = (int)(col - N2C);
        int hh = cv >> 6, dd = cv & 63;
        int bb = (int)(row >> 11);
        long t = row & 2047;
        f16x2 lo = __builtin_bit_cast(f16x2, __builtin_amdgcn_cvt_pkrtz(v0, v1));
        f16x2 hi = __builtin_bit_cast(f16x2, __builtin_amdgcn_cvt_pkrtz(v2, v3));
        f16x4 w; w[0] = lo[0]; w[1] = lo[1]; w[2] = hi[0]; w[3] = hi[1];
        *(f16x4*)&vt[(((long)bb * H_ + hh) * HD_ + dd) * T_ + t] = w;
      }
    }
  }
}

// -------- proj GEMM: 128x64 tiles (1024 blocks = 4/CU) --------
__global__ __launch_bounds__(256) void gemm_proj(
    const u16* __restrict__ A, const u16* __restrict__ Bt,
    const float* __restrict__ bias, float* __restrict__ Cout) {
  __shared__ u16 As[128 * 64];   // 16 KB
  __shared__ u16 Bs[64 * 64];    //  8 KB
  const int tid = threadIdx.x;
  const int wave = tid >> 6, lane = tid & 63;
  const int l15 = lane & 15, quad = lane >> 4;
  const int rA = lane >> 3, cxor = (lane & 7) ^ rA;
  const long rowA0 = (long)blockIdx.x * 128;
  const long colB0 = (long)blockIdx.y * 64;
  const int K = C_;

  f32x4 acc[2][4] = {};

  const u16* Ag = A + (rowA0 + wave * 32 + rA) * K + cxor * 8;
  const u16* Bg = Bt + (colB0 + wave * 16 + rA) * K + cxor * 8;
  u16* Asw = &As[(wave * 32) * 64];
  u16* Bsw = &Bs[(wave * 16) * 64];

  const int fbase = l15 * 64 + ((quad ^ (l15 & 3)) << 3) + (((l15 >> 2) & 1) << 5);
  const int aA0 = wave * 2048 + fbase, aA1 = aA0 ^ 32;
  const int bA0 = fbase, bA1 = bA0 ^ 32;

  for (int k0 = 0; k0 < K; k0 += 64) {
    #pragma unroll
    for (int j = 0; j < 4; ++j)
      GLD16(Ag + (long)j * 8 * K + k0, Asw + j * 8 * 64);
    #pragma unroll
    for (int j = 0; j < 2; ++j)
      GLD16(Bg + (long)j * 8 * K + k0, Bsw + j * 8 * 64);
    __syncthreads();
    #pragma unroll
    for (int kk = 0; kk < 2; ++kk) {
      const int ai = kk ? aA1 : aA0;
      const int bi = kk ? bA1 : bA0;
      bf16x8 af[2], bfr[4];
      #pragma unroll
      for (int mt = 0; mt < 2; ++mt)
        af[mt] = *(const bf16x8*)&As[ai + mt * 1024];
      #pragma unroll
      for (int nt = 0; nt < 4; ++nt)
        bfr[nt] = *(const bf16x8*)&Bs[bi + nt * 1024];
      #pragma unroll
      for (int mt = 0; mt < 2; ++mt)
        #pragma unroll
        for (int nt = 0; nt < 4; ++nt)
          acc[mt][nt] = __builtin_amdgcn_mfma_f32_16x16x32_bf16(
              af[mt], bfr[nt], acc[mt][nt], 0, 0, 0);
    }
    __syncthreads();
  }

  float bl[4];
  #pragma unroll
  for (int nt = 0; nt < 4; ++nt)
    bl[nt] = bias[colB0 + nt * 16 + l15];
  #pragma unroll
  for (int mt = 0; mt < 2; ++mt) {
    long row = rowA0 + wave * 32 + mt * 16 + quad * 4;
    #pragma unroll
    for (int nt = 0; nt < 4; ++nt) {
      long col = colB0 + nt * 16 + l15;
      #pragma unroll
      for (int r = 0; r < 4; ++r)
        Cout[(row + r) * C_ + col] = acc[mt][nt][r] + bl[nt];
    }
  }
}

// ---------------- flash attention v11 ----------------
// 2 waves x 32 q-rows per 64q block (block=128): each kf/vf LDS fragment
// feeds TWO MFMAs (two 16-q groups per wave) -> K/V LDS read redundancy
// halves (80 KB -> 48 KB per tile-unit incl. staging). Grid/balance/swizzle
// and all math identical to v10.
__global__ __launch_bounds__(128) void flash_attn(
    const u16* __restrict__ qk, const f16* __restrict__ vt,
    u16* __restrict__ yb) {
  __shared__ u16 KsF[2 * 64 * 64];   // 16 KB (double-buffered)
  __shared__ f16 VsF[2 * 64 * 64];   // 16 KB (double-buffered)
  const int l = blockIdx.x;          // 0..2047
  const int bh = l & 63;             // same bh%8 -> same XCD
  const int qt = 31 - (l >> 6);      // longest blocks dispatch first
  const int b = bh >> 4, h = bh & 15;
  const int tid = threadIdx.x, wave = tid >> 6, lane = tid & 63;
  const int l15 = lane & 15, quad = lane >> 4;
  const int rA = lane >> 3, cxor = (lane & 7) ^ rA;

  const u16* Qb = qk + (long)b * T_ * N2C + h * HD_;
  const f16* Vbase = vt + (long)bh * HD_ * T_;
  // staging: wave w covers rows w*32 + j*8 + rA (j=0..3), chunk cxor
  const u16* Kb0 = Qb + C_ + (long)(wave * 32 + rA) * N2C + cxor * 8;
  const f16* Vb0 = Vbase + (long)(wave * 32 + rA) * T_ + cxor * 8;

  u16* ksw0 = &KsF[(wave * 32) * 64];
  u16* ksw1 = &KsF[4096 + (wave * 32) * 64];
  f16* vsw0 = &VsF[(wave * 32) * 64];
  f16* vsw1 = &VsF[4096 + (wave * 32) * 64];

  // hoisted fragment bases (elements); wave-independent (k-row indexed)
  const int kA0 = l15 * 64 + ((quad ^ (l15 & 3)) << 3) + (((l15 >> 2) & 1) << 5);
  const int kA1 = kA0 ^ 32;
  const int vA0 = l15 * 64 + (((quad >> 1) ^ (l15 & 7)) << 3) + ((quad & 1) << 2);

  const float cs = 0.125f * 1.44269504088896340736f;  // 1/sqrt(HD) * log2(e)

#define FA_TILE(KT, BUF) do {                                                  \
    __syncthreads(); /* drains this tile's K+V GLD16 */                        \
    if ((KT) + 1 < nKT) {                                                      \
      u16* kd = (BUF) ? ksw0 : ksw1;                                           \
      f16* vd = (BUF) ? vsw0 : vsw1;                                           \
      GLD16(kp, kd);                                                           \
      GLD16(kp + 8 * N2C, kd + 8 * 64);                                        \
      GLD16(kp + 16 * N2C, kd + 16 * 64);                                      \
      GLD16(kp + 24 * N2C, kd + 24 * 64);                                      \
      GLD16(vp, vd);                                                           \
      GLD16(vp + 8 * T_, vd + 8 * 64);                                         \
      GLD16(vp + 16 * T_, vd + 16 * 64);                                       \
      GLD16(vp + 24 * T_, vd + 24 * 64);                                       \
      kp += 64 * N2C;                                                          \
      vp += 64;                                                                \
    }                                                                          \
    f32x4 St[2][4] = {};                                                       \
    _Pragma("unroll")                                                          \
    for (int kk = 0; kk < 2; ++kk) {                                           \
      const int ki = ((kk ? kA1 : kA0)) + (BUF) * 4096;                        \
      _Pragma("unroll")                                                        \
      for (int mt = 0; mt < 4; ++mt) {                                         \
        bf16x8 kf = *(const bf16x8*)&KsF[ki + mt * 1024];                      \
        St[0][mt] = __builtin_amdgcn_mfma_f32_16x16x32_bf16(                   \
            kf, bq[0][kk], St[0][mt], 0, 0, 0);                                \
        St[1][mt] = __builtin_amdgcn_mfma_f32_16x16x32_bf16(                   \
            kf, bq[1][kk], St[1][mt], 0, 0, 0);                                \
      }                                                                        \
    }                                                                          \
    if ((KT) == qt) {                                                          \
      _Pragma("unroll")                                                        \
      for (int g = 0; g < 2; ++g)                                              \
        _Pragma("unroll")                                                      \
        for (int mt = 0; mt < 4; ++mt)                                         \
          _Pragma("unroll")                                                    \
          for (int r = 0; r < 4; ++r)                                          \
            if (mt * 16 + quad * 4 + r > wave * 32 + g * 16 + l15)             \
              St[g][mt][r] = -__builtin_inff();                                \
    }                                                                          \
    f16x4 pf[2][4];                                                            \
    _Pragma("unroll")                                                          \
    for (int g = 0; g < 2; ++g) {                                              \
      float ps = 0.f;                                                          \
      _Pragma("unroll")                                                        \
      for (int mt = 0; mt < 4; ++mt) {                                         \
        float p0 = EXP2F(__builtin_fmaf(St[g][mt][0], cs, nref[g]));           \
        float p1 = EXP2F(__builtin_fmaf(St[g][mt][1], cs, nref[g]));           \
        float p2 = EXP2F(__builtin_fmaf(St[g][mt][2], cs, nref[g]));           \
        float p3 = EXP2F(__builtin_fmaf(St[g][mt][3], cs, nref[g]));           \
        ps += (p0 + p1) + (p2 + p3);                                           \
        f16x2 lo = __builtin_bit_cast(f16x2,                                   \
                                      __builtin_amdgcn_cvt_pkrtz(p0, p1));     \
        f16x2 hi = __builtin_bit_cast(f16x2,                                   \
                                      __builtin_amdgcn_cvt_pkrtz(p2, p3));     \
        pf[g][mt][0] = lo[0]; pf[g][mt][1] = lo[1];                            \
        pf[g][mt][2] = hi[0]; pf[g][mt][3] = hi[1];                            \
      }                                                                        \
      li[g] += ps;                                                             \
    }                                                                          \
    _Pragma("unroll")                                                          \
    for (int kc = 0; kc < 4; ++kc) {                                           \
      const int vi = (vA0 ^ (kc << 4)) + (BUF) * 4096;                         \
      _Pragma("unroll")                                                        \
      for (int dt = 0; dt < 4; ++dt) {                                         \
        f16x4 vf = *(const f16x4*)&VsF[vi + dt * 1024];                        \
        o[0][dt] = __builtin_amdgcn_mfma_f32_16x16x16f16(                      \
            vf, pf[0][kc], o[0][dt], 0, 0, 0);                                 \
        o[1][dt] = __builtin_amdgcn_mfma_f32_16x16x16f16(                      \
            vf, pf[1][kc], o[1][dt], 0, 0, 0);                                 \
      }                                                                        \
    }                                                                          \
  } while (0)

  const int nKT = qt + 1;
  // two 16-q groups per wave: q = qt*64 + wave*32 + g*16 + l15
  bf16x8 bq[2][2];
  float nref[2], li[2] = {0.f, 0.f};
  #pragma unroll
  for (int g = 0; g < 2; ++g) {
    const int qrow = qt * 64 + wave * 32 + g * 16 + l15;
    bq[g][0] = *(const bf16x8*)&Qb[(long)qrow * N2C + quad * 8];
    bq[g][1] = *(const bf16x8*)&Qb[(long)qrow * N2C + 32 + quad * 8];
    float qq = 0.f;
    #pragma unroll
    for (int j = 0; j < 8; ++j) {
      float a = (float)bq[g][0][j], bv = (float)bq[g][1][j];
      qq = __builtin_fmaf(a, a, qq);
      qq = __builtin_fmaf(bv, bv, qq);
    }
    qq += __shfl_xor(qq, 16);
    qq += __shfl_xor(qq, 32);
    nref[g] = -qq * cs;
  }

  const u16* kp = Kb0;
  const f16* vp = Vb0;

  // preload tile 0
  GLD16(kp, ksw0);
  GLD16(kp + 8 * N2C, ksw0 + 8 * 64);
  GLD16(kp + 16 * N2C, ksw0 + 16 * 64);
  GLD16(kp + 24 * N2C, ksw0 + 24 * 64);
  GLD16(vp, vsw0);
  GLD16(vp + 8 * T_, vsw0 + 8 * 64);
  GLD16(vp + 16 * T_, vsw0 + 16 * 64);
  GLD16(vp + 24 * T_, vsw0 + 24 * 64);
  kp += 64 * N2C;
  vp += 64;

  f32x4 o[2][4] = {};

  int kt = 0;
  #pragma unroll 1
  for (; kt + 1 < nKT; kt += 2) {
    FA_TILE(kt, 0);
    FA_TILE(kt + 1, 1);
  }
  if (nKT & 1) FA_TILE(nKT - 1, 0);

  #pragma unroll
  for (int g = 0; g < 2; ++g) {
    li[g] += __shfl_xor(li[g], 16);
    li[g] += __shfl_xor(li[g], 32);
    float inv = 1.f / li[g];
    const long qrow = qt * 64 + wave * 32 + g * 16 + l15;
    #pragma unroll
    for (int dt = 0; dt < 4; ++dt) {
      ushort4 w;
      w.x = f2bf(o[g][dt][0] * inv);
      w.y = f2bf(o[g][dt][1] * inv);
      w.z = f2bf(o[g][dt][2] * inv);
      w.w = f2bf(o[g][dt][3] * inv);
      *(ushort4*)&yb[((long)b * T_ + qrow) * C_ + h * HD_ + dt * 16 + quad * 4] = w;
    }
  }
#undef FA_TILE
}

extern "C" void kernel_launch(void* const* d_in, const int* in_sizes, int n_in,
                              void* d_out, int out_size, void* d_ws, size_t ws_size,
                              hipStream_t stream) {
  const float* x      = (const float*)d_in[0];
  const float* W_attn = (const float*)d_in[1];
  const float* b_attn = (const float*)d_in[2];
  const float* W_proj = (const float*)d_in[3];
  const float* b_proj = (const float*)d_in[4];
  float* out = (float*)d_out;

  char* ws = (char*)d_ws;
  u16* xb   = (u16*)(ws);                      // 8192*1024*2  = 16777216
  u16* W1t  = (u16*)(ws + 16777216);           // 3072*1024*2  =  6291456
  u16* W2t  = (u16*)(ws + 23068672);           // 1024*1024*2  =  2097152
  u16* qkb  = (u16*)(ws + 25165824);           // 8192*2048*2  = 33554432
  f16* vtb  = (f16*)(ws + 58720256);           // 64*64*2048*2 = 16777216
  u16* yb   = (u16*)(ws + 75497472);           // 8192*1024*2  = 16777216
  // total: 92274688 bytes

  prep<<<dim3(12288), dim3(256), 0, stream>>>(x, W_attn, W_proj, xb, W1t, W2t);
  gemm_qkv<<<dim3(M_ / 128, N3C / 128), dim3(256), 0, stream>>>(
      xb, W1t, b_attn, qkb, vtb);
  flash_attn<<<dim3(2048), dim3(128), 0, stream>>>(qkb, vtb, yb);
  gemm_proj<<<dim3(M_ / 128, C_ / 64), dim3(256), 0, stream>>>(
      yb, W2t, b_proj, out);
}